// Round 1
// baseline (10926.982 us; speedup 1.0000x reference)
//
#include <hip/hip_runtime.h>
#include <cmath>

#define TT 512
#define BB 32
#define HH 100
#define EE 50
#define NL 5
#define VV 10000
#define NBL 10      // blocks per layer (column-split)
#define JS 10       // hidden-slice per block
#define COLS 40     // 4 gates * JS
#define RS 16       // ring slots (power of 2)

__device__ __forceinline__ float sigmf(float x) { return 1.f / (1.f + __expf(-x)); }

// Wavefront-pipelined LSTM recurrence. Block (l,q): layer l, hidden slice
// [q*JS, q*JS+JS). Weights for the slice live in LDS; h exchanged through a
// global ring buffer with device-scope release/acquire flags.
__global__ __launch_bounds__(256) void lstm_rec_kernel(
    const int* __restrict__ toks, const float* __restrict__ emb,
    const float* __restrict__ Wx0, const float* __restrict__ Wh0, const float* __restrict__ b0,
    const float* __restrict__ WxU, const float* __restrict__ WhU, const float* __restrict__ bU,
    float* __restrict__ ring, float* __restrict__ h4,
    int* __restrict__ cnt, int* __restrict__ ccnt)
{
    const int l = blockIdx.x / NBL;
    const int q = blockIdx.x % NBL;
    const int tid = threadIdx.x;

    __shared__ float Wxs[HH * COLS];   // 16000 B
    __shared__ float Whs[HH * COLS];   // 16000 B
    __shared__ float bs[COLS];
    __shared__ float xs[BB * HH];      // 12800 B (stride 100: wave spans 8 b's -> conflict-free)
    __shared__ float hs[BB * HH];      // 12800 B
    __shared__ float gs[BB * 41];      // gate staging, padded stride
    __shared__ float cs[BB * JS];      // persistent cell state slice

    const float* WxL = (l == 0) ? Wx0 : WxU + (size_t)(l - 1) * HH * 400;
    const float* WhL = (l == 0) ? Wh0 : WhU + (size_t)(l - 1) * HH * 400;
    const float* bL  = (l == 0) ? b0  : bU  + (size_t)(l - 1) * 400;
    const int Kx = (l == 0) ? EE : HH;

    // one-time weight staging: local col c -> global gate col (c/JS)*100 + q*JS + c%JS
    for (int idx = tid; idx < Kx * COLS; idx += 256) {
        int k = idx / COLS, c = idx % COLS;
        Wxs[idx] = WxL[k * 400 + (c / JS) * HH + q * JS + (c % JS)];
    }
    for (int idx = tid; idx < HH * COLS; idx += 256) {
        int k = idx / COLS, c = idx % COLS;
        Whs[idx] = WhL[k * 400 + (c / JS) * HH + q * JS + (c % JS)];
    }
    for (int c = tid; c < COLS; c += 256)
        bs[c] = bL[(c / JS) * HH + q * JS + (c % JS)];
    for (int idx = tid; idx < BB * JS; idx += 256) cs[idx] = 0.f;
    __syncthreads();

    const int tc = tid & 7;    // 8 col-groups, each owns 5 cols (c = tc + 8*ii)
    const int b  = tid >> 3;   // 0..31

    for (int t = 0; t < TT; ++t) {
        if (tid == 0) {
            int spins = 0;
            // back-pressure: don't overwrite ring slot t%RS until layer l+1 consumed t-RS
            if (l < NL - 1 && t >= RS) {
                for (int qq = 0; qq < NBL; ++qq)
                    while (__hip_atomic_load(&ccnt[(l + 1) * NBL + qq], __ATOMIC_ACQUIRE,
                                             __HIP_MEMORY_SCOPE_AGENT) < t - RS + 1)
                        { if (++spins > 30000000) break; }
            }
            // x availability from layer below
            if (l > 0)
                while (__hip_atomic_load(&cnt[(l - 1) * TT + t], __ATOMIC_ACQUIRE,
                                         __HIP_MEMORY_SCOPE_AGENT) < NBL)
                    { if (++spins > 30000000) break; }
            // own-layer h[t-1] (all sibling slices)
            if (t > 0)
                while (__hip_atomic_load(&cnt[l * TT + (t - 1)], __ATOMIC_ACQUIRE,
                                         __HIP_MEMORY_SCOPE_AGENT) < NBL)
                    { if (++spins > 30000000) break; }
        }
        __syncthreads();

        // stage x
        if (l == 0) {
            for (int idx = tid; idx < BB * EE; idx += 256) {
                int bb = idx / EE, e = idx % EE;
                int tok = toks[bb * TT + t];
                xs[bb * HH + e] = emb[(size_t)tok * EE + e];
            }
        } else {
            const float* src = ring + (size_t)((l - 1) * RS + (t & (RS - 1))) * (BB * HH);
            for (int idx = tid; idx < BB * HH; idx += 256) xs[idx] = src[idx];
        }
        // stage h[t-1]
        if (t == 0) {
            for (int idx = tid; idx < BB * HH; idx += 256) hs[idx] = 0.f;
        } else {
            const float* src = (l == NL - 1)
                ? (h4 + (size_t)(t - 1) * (BB * HH))
                : (ring + (size_t)(l * RS + ((t - 1) & (RS - 1))) * (BB * HH));
            for (int idx = tid; idx < BB * HH; idx += 256) hs[idx] = src[idx];
        }
        __syncthreads();
        // publish consumption progress (reads of ring[l-1][t] are done)
        if (tid == 0 && l > 0)
            __hip_atomic_store(&ccnt[l * NBL + q], t + 1, __ATOMIC_RELEASE,
                               __HIP_MEMORY_SCOPE_AGENT);

        // g[b][c] = x.Wx + h.Wh + bias for this block's 40 cols
        float acc[5];
        #pragma unroll
        for (int ii = 0; ii < 5; ++ii) acc[ii] = bs[tc + 8 * ii];
        for (int k = 0; k < Kx; ++k) {
            float x0 = xs[b * HH + k];
            #pragma unroll
            for (int ii = 0; ii < 5; ++ii)
                acc[ii] = fmaf(x0, Wxs[k * COLS + tc + 8 * ii], acc[ii]);
        }
        for (int k = 0; k < HH; ++k) {
            float h0 = hs[b * HH + k];
            #pragma unroll
            for (int ii = 0; ii < 5; ++ii)
                acc[ii] = fmaf(h0, Whs[k * COLS + tc + 8 * ii], acc[ii]);
        }
        #pragma unroll
        for (int ii = 0; ii < 5; ++ii) gs[b * 41 + tc + 8 * ii] = acc[ii];
        __syncthreads();

        // elementwise LSTM cell for this block's (b, jj) slice; gate order i,f,o,ct
        for (int idx = tid; idx < BB * JS; idx += 256) {
            int bb = idx / JS, jj = idx % JS;
            float gi = gs[bb * 41 + jj];
            float gf = gs[bb * 41 + JS + jj];
            float go = gs[bb * 41 + 2 * JS + jj];
            float gc = gs[bb * 41 + 3 * JS + jj];
            float cold = cs[idx];
            float cn = sigmf(gf) * cold + sigmf(gi) * tanhf(gc);
            float hn = sigmf(go) * tanhf(cn);
            cs[idx] = cn;
            int gj = q * JS + jj;
            if (l < NL - 1)
                ring[(size_t)(l * RS + (t & (RS - 1))) * (BB * HH) + bb * HH + gj] = hn;
            else
                h4[(size_t)t * (BB * HH) + bb * HH + gj] = hn;
        }
        __threadfence();
        __syncthreads();
        if (tid == 0)
            __hip_atomic_fetch_add(&cnt[l * TT + t], 1, __ATOMIC_RELEASE,
                                   __HIP_MEMORY_SCOPE_AGENT);
    }
}

// out[b*512+t][v] = h4[t][b][:] . fc_w[:,v] + fc_b[v]; 64x64 tiles, K=100 single tile.
__global__ __launch_bounds__(256) void fc_kernel(
    const float* __restrict__ h4, const float* __restrict__ fcw,
    const float* __restrict__ fcb, float* __restrict__ out)
{
    const int v0 = blockIdx.x * 64;
    const int R0 = blockIdx.y * 64;   // 64 consecutive rows r=b*512+t share one b
    const int tid = threadIdx.x;
    __shared__ float As[64 * 104];
    __shared__ float Bs[100 * 64];
    const int b = R0 >> 9;
    const int t0 = R0 & 511;
    for (int idx = tid; idx < 64 * HH; idx += 256) {
        int rl = idx / HH, k = idx % HH;
        As[rl * 104 + k] = h4[(size_t)(t0 + rl) * (BB * HH) + b * HH + k];
    }
    for (int idx = tid; idx < HH * 64; idx += 256) {
        int k = idx / 64, vl = idx % 64;
        int v = v0 + vl;
        Bs[idx] = (v < VV) ? fcw[(size_t)k * VV + v] : 0.f;
    }
    __syncthreads();
    const int tv = tid & 15, tr = tid >> 4;
    float acc[4][4] = {{0.f}};
    for (int k = 0; k < HH; ++k) {
        float a[4], bv[4];
        #pragma unroll
        for (int rr = 0; rr < 4; ++rr) a[rr] = As[(tr + 16 * rr) * 104 + k];
        #pragma unroll
        for (int vv = 0; vv < 4; ++vv) bv[vv] = Bs[k * 64 + tv + 16 * vv];
        #pragma unroll
        for (int rr = 0; rr < 4; ++rr)
            #pragma unroll
            for (int vv = 0; vv < 4; ++vv)
                acc[rr][vv] = fmaf(a[rr], bv[vv], acc[rr][vv]);
    }
    #pragma unroll
    for (int rr = 0; rr < 4; ++rr) {
        size_t r = (size_t)R0 + tr + 16 * rr;
        #pragma unroll
        for (int vv = 0; vv < 4; ++vv) {
            int v = v0 + tv + 16 * vv;
            if (v < VV) out[r * VV + v] = acc[rr][vv] + fcb[v];
        }
    }
}

extern "C" void kernel_launch(void* const* d_in, const int* in_sizes, int n_in,
                              void* d_out, int out_size, void* d_ws, size_t ws_size,
                              hipStream_t stream)
{
    const int*   toks = (const int*)d_in[0];
    const float* emb  = (const float*)d_in[1];
    const float* Wx0  = (const float*)d_in[2];
    const float* Wh0  = (const float*)d_in[3];
    const float* b0   = (const float*)d_in[4];
    const float* WxU  = (const float*)d_in[5];
    const float* WhU  = (const float*)d_in[6];
    const float* bU   = (const float*)d_in[7];
    const float* fcw  = (const float*)d_in[8];
    const float* fcb  = (const float*)d_in[9];
    float* out = (float*)d_out;

    // ws layout: [cnt 5*512 ints][ccnt 50 ints] | pad to 16K | ring 4*RS*3200 f32 | h4 512*3200 f32
    char* ws   = (char*)d_ws;
    int*  cnt  = (int*)ws;
    int*  ccnt = (int*)(ws + NL * TT * 4);
    float* ring = (float*)(ws + 16384);
    float* h4   = (float*)(ws + 16384 + (size_t)(NL - 1) * RS * BB * HH * 4);

    hipMemsetAsync(ws, 0, NL * TT * 4 + NL * NBL * 4, stream);
    lstm_rec_kernel<<<NL * NBL, 256, 0, stream>>>(toks, emb, Wx0, Wh0, b0,
                                                  WxU, WhU, bU, ring, h4, cnt, ccnt);
    fc_kernel<<<dim3((VV + 63) / 64, (BB * TT) / 64), 256, 0, stream>>>(h4, fcw, fcb, out);
}